// Round 7
// baseline (502.062 us; speedup 1.0000x reference)
//
#include <hip/hip_runtime.h>
#include <cmath>

#define NPTS 4096
#define NPOINT 204   // int(4096 * 0.05)
#define NPCT 5
#define FPS_T 256
#define NGROUP 408   // B * NPOINT
#define NPART (NGROUP * NPCT)
#define GPTS_TOT 1265   // sum(ns_p + 8) = 89+171+253+335+417

typedef unsigned long long u64;

struct LossParams {
    float r2[NPCT];
    float wscale[NPCT];   // (p*100)^2 / (B*NPOINT*NPCT)
    float expect_len;
};

// per-pct compile-time constants
__device__ __forceinline__ constexpr int NSC(int p) {
    return p == 0 ? 81 : p == 1 ? 163 : p == 2 ? 245 : p == 3 ? 327 : 409;
}
__device__ __forceinline__ constexpr int OFFC(int p) {
    return p == 0 ? 0 : p == 1 ? 89 : p == 2 ? 260 : p == 3 ? 513 : 848;
}

// ---------------- DPP wave64 reductions ------------------------------------
template <int CTRL>
__device__ __forceinline__ int dpp_imax(int v) {
    int t = __builtin_amdgcn_update_dpp(0, v, CTRL, 0xf, 0xf, true);
    return v > t ? v : t;
}
template <int CTRL>
__device__ __forceinline__ int dpp_imin(int v) {
    int t = __builtin_amdgcn_update_dpp(0x7fffffff, v, CTRL, 0xf, 0xf, false);
    return v < t ? v : t;
}
__device__ __forceinline__ int wave_max_i(int v) {
    v = dpp_imax<0x111>(v); v = dpp_imax<0x112>(v);
    v = dpp_imax<0x114>(v); v = dpp_imax<0x118>(v);
    v = dpp_imax<0x142>(v); v = dpp_imax<0x143>(v);
    return __builtin_amdgcn_readlane(v, 63);
}
__device__ __forceinline__ int wave_min_i(int v) {
    v = dpp_imin<0x111>(v); v = dpp_imin<0x112>(v);
    v = dpp_imin<0x114>(v); v = dpp_imin<0x118>(v);
    v = dpp_imin<0x142>(v); v = dpp_imin<0x143>(v);
    return __builtin_amdgcn_readlane(v, 63);
}
template <int CTRL>
__device__ __forceinline__ u64 dpp_u64max(u64 v) {
    int lo = (int)(unsigned)v;
    int hi = (int)(unsigned)(v >> 32);
    unsigned slo = (unsigned)__builtin_amdgcn_update_dpp(0, lo, CTRL, 0xf, 0xf, true);
    unsigned shi = (unsigned)__builtin_amdgcn_update_dpp(0, hi, CTRL, 0xf, 0xf, true);
    u64 o = ((u64)shi << 32) | slo;
    return v > o ? v : o;
}

// ---------------------------------------------------------------------------
// Kernel 1: FPS, one block per batch, 256 threads. Per-thread argmax over
// 16 candidates now an adjacent-pair TREE (depth 4, tie keeps LEFT =
// smaller index — adjacent pairing keeps every left block's indices strictly
// below the right block's, so first-occurrence semantics are exact).
// Then int-bits DPP wave max + tie-index DPP wave min, 1 barrier (ping-pong
// keys), lane-parallel 4-key u64 merge. Distance: fp contract OFF,
// ((dx^2+dy^2)+dz^2) order (matches numpy ref).
// ---------------------------------------------------------------------------
__global__ __launch_bounds__(FPS_T) void fps_kernel(const float* __restrict__ pcd,
                                                    int* __restrict__ fps_idx) {
#pragma clang fp contract(off)
    __shared__ float4 pts[NPTS];        // 64 KB
    __shared__ u64 keys[2][4];          // ping-pong: 1 barrier/iter

    const int b = blockIdx.x;
    const int t = threadIdx.x;
    const int wave = t >> 6, lane = t & 63;
    const float* base = pcd + (size_t)b * NPTS * 3;

    float x[16], y[16], z[16], dist[16];
    #pragma unroll
    for (int k = 0; k < 16; ++k) {
        int n = k * FPS_T + t;
        float vx = base[3 * n + 0];
        float vy = base[3 * n + 1];
        float vz = base[3 * n + 2];
        pts[n] = make_float4(vx, vy, vz, 0.0f);
        x[k] = vx; y[k] = vy; z[k] = vz;
        dist[k] = 1e10f;
    }
    int* out = fps_idx + b * NPOINT;
    if (t == 0) out[0] = 0;
    __syncthreads();

    float4 c = pts[0];
    for (int it = 1; it < NPOINT; ++it) {
        int bv[16], kv[16];
        #pragma unroll
        for (int k = 0; k < 16; ++k) {
            float dx = x[k] - c.x, dy = y[k] - c.y, dz = z[k] - c.z;
            float d  = (dx * dx + dy * dy) + dz * dz;
            float dk = fminf(dist[k], d);
            dist[k] = dk;
            bv[k] = __float_as_int(dk);      // nonneg: int cmp == float cmp
            kv[k] = k;
        }
        // adjacent-pair tree argmax, tie -> left (smaller index)
        #pragma unroll
        for (int st = 1; st < 16; st <<= 1) {
            #pragma unroll
            for (int j = 0; j < 16; j += 2 * st) {
                bool kp = bv[j] >= bv[j + st];
                bv[j] = kp ? bv[j] : bv[j + st];
                kv[j] = kp ? kv[j] : kv[j + st];
            }
        }
        int bb = bv[0];
        int bi = (kv[0] << 8) + t;           // k*256 + t
        int wmax = wave_max_i(bb);
        int cand = (bb == wmax) ? bi : 0x7fffffff;
        int widx = wave_min_i(cand);         // smallest index among ties
        if (lane == 0)
            keys[it & 1][wave] =
                ((u64)(unsigned)wmax << 32) | (unsigned)~(unsigned)widx;
        __syncthreads();
        u64 kk = keys[it & 1][lane & 3];     // 16-rows hold identical copies
        kk = dpp_u64max<0x111>(kk);
        kk = dpp_u64max<0x112>(kk);          // lane 16r+3 holds global max
        unsigned lo3 = (unsigned)__builtin_amdgcn_readlane((int)(unsigned)kk, 3);
        int last = (int)~lo3;
        c = pts[last];
        if (t == 0) out[it] = last;
    }
}

// ---------------------------------------------------------------------------
// Kernel 2: ONE block per group (408 blocks); all 5 percentages fused.
// Phase A: each wave owns a contiguous 1024-pt segment; coords + d^2 for its
// 16 sub-chunks held in VGPRs (NO u64 mask arrays — pass 2 re-ballots from
// the stored d^2). 5 ballot-compactions into 5 disjoint LDS regions, all
// order-preserving (pn2 truncation semantics).
// Phase B x5: min2-incl-self via med3 (exact reference k=2 KNN); pads
// analytic (0.1 each; region-first point's nn = 0 iff padded).
// ---------------------------------------------------------------------------
__global__ __launch_bounds__(256) void group_kernel(const float* __restrict__ pcd,
                                                    const int* __restrict__ fps_idx,
                                                    float* __restrict__ partials,
                                                    LossParams P) {
    const int g = blockIdx.x;              // 0 .. NGROUP-1
    const int b = g / NPOINT;
    const int m = g - b * NPOINT;
    const int t = threadIdx.x;
    const int wave = t >> 6, lane = t & 63;

    __shared__ float4 gpts[GPTS_TOT];      // 19.8 KB, 5 regions
    __shared__ int    s_wtot[NPCT][4];
    __shared__ float  s_part[NPCT][4];

    const float* base = pcd + (size_t)b * NPTS * 3;
    int qi = fps_idx[b * NPOINT + m];
    float qx = base[3 * qi + 0], qy = base[3 * qi + 1], qz = base[3 * qi + 2];

    // ---- Phase A pass 1: d^2 once, 5 counts ----
    float xx[16], yy[16], zz[16], dd[16];
    int run[NPCT] = {0, 0, 0, 0, 0};
    #pragma unroll 4
    for (int s = 0; s < 16; ++s) {
        int n = wave * 1024 + s * 64 + lane;
        float X = base[3 * n + 0];
        float Y = base[3 * n + 1];
        float Z = base[3 * n + 2];
        xx[s] = X; yy[s] = Y; zz[s] = Z;
        float d2;
        {
#pragma clang fp contract(off)
            float dx = qx - X, dy = qy - Y, dz = qz - Z;
            float aa = dx * dx, bb = dy * dy, cc = dz * dz;
            d2 = (aa + bb) + cc;
        }
        dd[s] = d2;
        #pragma unroll
        for (int p = 0; p < NPCT; ++p)
            run[p] += __popcll(__ballot(d2 < P.r2[p]));   // strict <
    }
    if (lane == 0) {
        #pragma unroll
        for (int p = 0; p < NPCT; ++p) s_wtot[p][wave] = run[p];
    }
    __syncthreads();
    int Bw[NPCT], cB[NPCT];
    #pragma unroll
    for (int p = 0; p < NPCT; ++p) {
        int w0 = s_wtot[p][0], w1 = s_wtot[p][1], w2 = s_wtot[p][2], w3 = s_wtot[p][3];
        Bw[p] = (wave > 0 ? w0 : 0) + (wave > 1 ? w1 : 0) + (wave > 2 ? w2 : 0);
        int cnt = w0 + w1 + w2 + w3;
        cB[p] = cnt < NSC(p) ? cnt : NSC(p);
    }

    // ---- Phase A pass 2: 5 ordered compactions (re-ballot from dd) ----
    #pragma unroll
    for (int p = 0; p < NPCT; ++p) {
        int run2 = Bw[p];
        #pragma unroll 4
        for (int s = 0; s < 16; ++s) {
            if (run2 >= NSC(p)) break;     // wave-uniform
            u64 mk = __ballot(dd[s] < P.r2[p]);
            bool in = (mk >> lane) & 1ull;
            int pos = run2 + __popcll(mk & ((1ull << lane) - 1ull));
            if (in && pos < NSC(p)) {
                float X = xx[s], Y = yy[s], Z = zz[s];
                float sq = fmaf(X, X, fmaf(Y, Y, Z * Z));
                gpts[OFFC(p) + pos] = make_float4(X, Y, Z, sq);
            }
            run2 += __popcll(mk);
        }
    }
    if (t < 8) {                           // sentinels for j-unroll (disjoint addrs)
        #pragma unroll
        for (int p = 0; p < NPCT; ++p)
            gpts[OFFC(p) + cB[p] + t] = make_float4(1e6f, 1e6f, 1e6f, 3e12f);
    }
    __syncthreads();

    // ---- Phase B x5: min2 incl. self via med3 ----
    float psum[NPCT];
    #pragma unroll
    for (int p = 0; p < NPCT; ++p) {
        const int c = cB[p];
        const float4* reg = gpts + OFFC(p);
        float sum = 0.0f;
        for (int i = t; i < c; i += 256) {
            float4 pi = reg[i];
            float m1 = 1e30f, m2 = 1e30f;
            for (int jt = 0; jt < c; jt += 8) {
                #pragma unroll
                for (int u = 0; u < 8; ++u) {
                    float4 a = reg[jt + u];
                    float tt = pi.x * a.x;
                    tt = fmaf(pi.y, a.y, tt);
                    tt = fmaf(pi.z, a.z, tt);
                    float h = fmaf(-2.0f, tt, a.w);      // |a|^2 - 2<pi,a>
                    m2 = __builtin_amdgcn_fmed3f(m1, m2, h);
                    m1 = fminf(m1, h);
                }
            }
            float d2m = fmaxf(pi.w + m2, 0.0f);
            // pads duplicate reg[0] => i=0's nn is exactly 0 when padded
            if (!(i == 0 && c < NSC(p))) sum += sqrtf(d2m);
        }
        psum[p] = sum;
    }
    #pragma unroll
    for (int p = 0; p < NPCT; ++p) {
        float s = psum[p];
        #pragma unroll
        for (int off = 32; off; off >>= 1) s += __shfl_down(s, off);
        if (lane == 0) s_part[p][wave] = s;
    }
    __syncthreads();
    if (t < NPCT) {
        int p = t;
        float tot = s_part[p][0] + s_part[p][1] + s_part[p][2] + s_part[p][3];
        float nsf = (float)(p == 0 ? 81 : p == 1 ? 163 : p == 2 ? 245 : p == 3 ? 327 : 409);
        tot += 0.1f * nsf;                 // every entry contributes |nn+0.1| = nn+0.1
        float u  = tot / nsf;
        float du = u - P.expect_len;
        float ws = p == 0 ? P.wscale[0] : p == 1 ? P.wscale[1] : p == 2 ? P.wscale[2]
                 : p == 3 ? P.wscale[3] : P.wscale[4];
        partials[g * NPCT + p] = du * du / (P.expect_len + 0.1f) * ws;
    }
}

// ---------------------------------------------------------------------------
// Kernel 3: sum the 2040 per-(group,pct) partials -> d_out (no atomics).
// ---------------------------------------------------------------------------
__global__ __launch_bounds__(256) void reduce_kernel(const float* __restrict__ partials,
                                                     float* __restrict__ out) {
    const int t = threadIdx.x;
    __shared__ float sp[4];
    float s = 0.0f;
    for (int i = t; i < NPART; i += 256) s += partials[i];
    #pragma unroll
    for (int off = 32; off; off >>= 1) s += __shfl_down(s, off);
    if ((t & 63) == 0) sp[t >> 6] = s;
    __syncthreads();
    if (t == 0) out[0] = sp[0] + sp[1] + sp[2] + sp[3];
}

extern "C" void kernel_launch(void* const* d_in, const int* in_sizes, int n_in,
                              void* d_out, int out_size, void* d_ws, size_t ws_size,
                              hipStream_t stream) {
    const float* pcd = (const float*)d_in[0];
    const int B = in_sizes[0] / (NPTS * 3);   // = 2
    float* out = (float*)d_out;
    int*   fps = (int*)d_ws;                  // [0, NGROUP) ints
    float* partials = (float*)d_ws + NGROUP;  // [NGROUP, NGROUP+NPART) floats

    fps_kernel<<<dim3(B), dim3(FPS_T), 0, stream>>>(pcd, fps);

    LossParams P;
    const double ps[NPCT] = {0.02, 0.04, 0.06, 0.08, 0.10};
    for (int i = 0; i < NPCT; ++i) {
        double r = std::sqrt(ps[i] * 1.0);
        P.r2[i] = (float)(r * r);
        double w = (ps[i] * 100.0) * (ps[i] * 100.0);
        P.wscale[i] = (float)(w / (double)(B * NPOINT * NPCT));
    }
    P.expect_len = (float)std::sqrt(3.14159265358979323846 / (double)NPTS);

    group_kernel<<<dim3(NGROUP), dim3(256), 0, stream>>>(pcd, fps, partials, P);
    reduce_kernel<<<dim3(1), dim3(256), 0, stream>>>(partials, out);
}

// Round 8
// 226.081 us; speedup vs baseline: 2.2207x; 2.2207x over previous
//
#include <hip/hip_runtime.h>
#include <cmath>

#define NPTS 4096
#define NPOINT 204   // int(4096 * 0.05)
#define NPCT 5
#define MAXNS 409    // int(4096 * 0.10)
#define FPS_T 256
#define NGROUP 408   // B * NPOINT
#define NPART (NGROUP * NPCT)

typedef unsigned long long u64;
typedef float f32x2 __attribute__((ext_vector_type(2)));

struct LossParams {
    int   nsample[NPCT];
    float r2[NPCT];
    float wscale[NPCT];   // (p*100)^2 / (B*NPOINT*NPCT)
    float expect_len;
};

// ---------------- DPP wave64 reductions ------------------------------------
template <int CTRL>
__device__ __forceinline__ int dpp_imax(int v) {
    int t = __builtin_amdgcn_update_dpp(0, v, CTRL, 0xf, 0xf, true);
    return v > t ? v : t;
}
template <int CTRL>
__device__ __forceinline__ int dpp_imin(int v) {
    int t = __builtin_amdgcn_update_dpp(0x7fffffff, v, CTRL, 0xf, 0xf, false);
    return v < t ? v : t;
}
__device__ __forceinline__ int wave_max_i(int v) {
    v = dpp_imax<0x111>(v); v = dpp_imax<0x112>(v);
    v = dpp_imax<0x114>(v); v = dpp_imax<0x118>(v);
    v = dpp_imax<0x142>(v); v = dpp_imax<0x143>(v);
    return __builtin_amdgcn_readlane(v, 63);
}
__device__ __forceinline__ int wave_min_i(int v) {
    v = dpp_imin<0x111>(v); v = dpp_imin<0x112>(v);
    v = dpp_imin<0x114>(v); v = dpp_imin<0x118>(v);
    v = dpp_imin<0x142>(v); v = dpp_imin<0x143>(v);
    return __builtin_amdgcn_readlane(v, 63);
}
template <int CTRL>
__device__ __forceinline__ u64 dpp_u64max(u64 v) {
    int lo = (int)(unsigned)v;
    int hi = (int)(unsigned)(v >> 32);
    unsigned slo = (unsigned)__builtin_amdgcn_update_dpp(0, lo, CTRL, 0xf, 0xf, true);
    unsigned shi = (unsigned)__builtin_amdgcn_update_dpp(0, hi, CTRL, 0xf, 0xf, true);
    u64 o = ((u64)shi << 32) | slo;
    return v > o ? v : o;
}

// ---------------------------------------------------------------------------
// Kernel 1: FPS — EXACT R5 kernel (proven 118.5 µs; R7's tree argmax spilled
// to scratch and regressed 3.3x — do not add per-thread arrays here).
// ---------------------------------------------------------------------------
__global__ __launch_bounds__(FPS_T) void fps_kernel(const float* __restrict__ pcd,
                                                    int* __restrict__ fps_idx) {
#pragma clang fp contract(off)
    __shared__ float4 pts[NPTS];        // 64 KB
    __shared__ u64 keys[2][4];          // ping-pong: 1 barrier/iter

    const int b = blockIdx.x;
    const int t = threadIdx.x;
    const int wave = t >> 6, lane = t & 63;
    const float* base = pcd + (size_t)b * NPTS * 3;

    f32x2 X[8], Y[8], Z[8], D[8];
    #pragma unroll
    for (int q = 0; q < 8; ++q) {
        int n0 = (2 * q) * FPS_T + t;
        int n1 = (2 * q + 1) * FPS_T + t;
        float x0 = base[3 * n0 + 0], y0 = base[3 * n0 + 1], z0 = base[3 * n0 + 2];
        float x1 = base[3 * n1 + 0], y1 = base[3 * n1 + 1], z1 = base[3 * n1 + 2];
        pts[n0] = make_float4(x0, y0, z0, 0.0f);
        pts[n1] = make_float4(x1, y1, z1, 0.0f);
        X[q] = (f32x2){x0, x1};
        Y[q] = (f32x2){y0, y1};
        Z[q] = (f32x2){z0, z1};
        D[q] = (f32x2){1e10f, 1e10f};
    }
    int* out = fps_idx + b * NPOINT;
    if (t == 0) out[0] = 0;
    __syncthreads();

    float4 c = pts[0];
    for (int it = 1; it < NPOINT; ++it) {
        f32x2 cxx = (f32x2){c.x, c.x};
        f32x2 cyy = (f32x2){c.y, c.y};
        f32x2 czz = (f32x2){c.z, c.z};
        int bb = -1, bi = 0;
        #pragma unroll
        for (int q = 0; q < 8; ++q) {
            f32x2 dx = X[q] - cxx, dy = Y[q] - cyy, dz = Z[q] - czz;
            f32x2 d  = (dx * dx + dy * dy) + dz * dz;
            f32x2 dd = D[q];
            float d0 = fminf(dd.x, d.x);
            float d1 = fminf(dd.y, d.y);
            D[q] = (f32x2){d0, d1};
            int b0 = __float_as_int(d0);
            int b1 = __float_as_int(d1);
            if (b0 > bb) { bb = b0; bi = (2 * q) * FPS_T + t; }
            if (b1 > bb) { bb = b1; bi = (2 * q + 1) * FPS_T + t; }
        }
        int wmax = wave_max_i(bb);
        int cand = (bb == wmax) ? bi : 0x7fffffff;
        int widx = wave_min_i(cand);
        if (lane == 0)
            keys[it & 1][wave] =
                ((u64)(unsigned)wmax << 32) | (unsigned)~(unsigned)widx;
        __syncthreads();
        u64 kv = keys[it & 1][lane & 3];
        kv = dpp_u64max<0x111>(kv);
        kv = dpp_u64max<0x112>(kv);
        unsigned lo3 = (unsigned)__builtin_amdgcn_readlane((int)(unsigned)kv, 3);
        int last = (int)~lo3;
        c = pts[last];
        if (t == 0) out[it] = last;
    }
}

// ---------------------------------------------------------------------------
// Kernel 2: one block per (group, percentage); pidx = blk % 5 (interleaved).
// NEW: stage the batch's 48 KB of points into LDS via coalesced float4 loads
// (12 dwordx4/thread, 1 L1 transaction each) — replaces the stride-3 scalar
// global loads whose 12-way transaction splitting was the ~90 µs bottleneck.
// Phase A (ballot compaction) reads sbuf[3n+c]: banks (3*lane)%32 = 2-way,
// conflict-free. Downstream math identical to R5/R6 (passing, absmax .0156).
// ---------------------------------------------------------------------------
__global__ __launch_bounds__(256) void group_kernel(const float* __restrict__ pcd,
                                                    const int* __restrict__ fps_idx,
                                                    float* __restrict__ partials,
                                                    LossParams P) {
    const int xid  = blockIdx.x;           // 0 .. NPART-1
    const int pidx = xid % NPCT;
    const int g    = xid / NPCT;           // 0 .. NGROUP-1
    const int b    = g / NPOINT;
    const int m    = g - b * NPOINT;
    const int t    = threadIdx.x;
    const int wave = t >> 6, lane = t & 63;

    const int   ns = P.nsample[pidx];
    const float r2 = P.r2[pidx];

    __shared__ float  sbuf[NPTS * 3];      // 48 KB staged batch
    __shared__ float4 gpts[MAXNS + 8];     // 6.7 KB compacted group
    __shared__ int    s_wtot[4];
    __shared__ float  s_part[4];

    // ---- Stage: coalesced float4 copy of the whole batch ----
    {
        const float4* src4 = (const float4*)(pcd + (size_t)b * NPTS * 3);
        float4* dst4 = (float4*)sbuf;
        #pragma unroll
        for (int i = 0; i < NPTS * 3 / 4 / 256; ++i)   // 12 iters
            dst4[i * 256 + t] = src4[i * 256 + t];
    }
    int qi = fps_idx[b * NPOINT + m];
    __syncthreads();
    const float qx = sbuf[3 * qi + 0], qy = sbuf[3 * qi + 1], qz = sbuf[3 * qi + 2];

    // ---- Phase A pass 1: ballot the wave's 16 sub-chunks of 64 points ----
    unsigned long long msk[16];
    int lbase[16];
    int run = 0;
    #pragma unroll 4
    for (int s = 0; s < 16; ++s) {
        int n = wave * 1024 + s * 64 + lane;
        float x = sbuf[3 * n + 0];
        float y = sbuf[3 * n + 1];
        float z = sbuf[3 * n + 2];
        float d2;
        {
#pragma clang fp contract(off)
            float dx = qx - x, dy = qy - y, dz = qz - z;
            float aa = dx * dx, bb = dy * dy, cc = dz * dz;
            d2 = (aa + bb) + cc;
        }
        msk[s] = __ballot(d2 < r2);        // strict <, matches reference
        lbase[s] = run;
        run += __popcll(msk[s]);
    }
    if (lane == 0) s_wtot[wave] = run;
    __syncthreads();
    int w0 = s_wtot[0], w1 = s_wtot[1], w2 = s_wtot[2], w3 = s_wtot[3];
    int Bw = (wave > 0 ? w0 : 0) + (wave > 1 ? w1 : 0) + (wave > 2 ? w2 : 0);
    int cnt  = w0 + w1 + w2 + w3;
    int cntB = cnt < ns ? cnt : ns;        // real points kept
    const int npad = ns - cntB;

    // ---- Phase A pass 2: ordered compaction into LDS, w = |p|^2 ----
    #pragma unroll 4
    for (int s = 0; s < 16; ++s) {
        int gb = Bw + lbase[s];            // wave-uniform
        if (gb >= ns) break;
        unsigned long long mk = msk[s];
        bool in = (mk >> lane) & 1ull;
        int pos = gb + __popcll(mk & ((1ull << lane) - 1ull));
        if (in && pos < ns) {
            int n = wave * 1024 + s * 64 + lane;
            float x = sbuf[3 * n], y = sbuf[3 * n + 1], z = sbuf[3 * n + 2];
            float sq = fmaf(x, x, fmaf(y, y, z * z));
            gpts[pos] = make_float4(x, y, z, sq);
        }
    }
    if (t < 8) gpts[cntB + t] = make_float4(1e6f, 1e6f, 1e6f, 3e12f);  // sentinels
    __syncthreads();

    // ---- Phase B: 2nd-smallest h (incl. self) via med3; d2 = sq_i + m2 ----
    float sum = 0.0f;
    if (cntB > 256) {
        const int i0 = t, i1 = t + 256;
        const bool a1 = i1 < cntB;
        float4 p0 = gpts[i0];
        float4 p1 = gpts[a1 ? i1 : 0];
        float m10 = 1e30f, m20 = 1e30f;
        float m11 = 1e30f, m21 = 1e30f;
        for (int jt = 0; jt < cntB; jt += 8) {
            #pragma unroll
            for (int u = 0; u < 8; ++u) {
                float4 a = gpts[jt + u];
                float tt, h;
                tt = p0.x * a.x; tt = fmaf(p0.y, a.y, tt); tt = fmaf(p0.z, a.z, tt);
                h = fmaf(-2.0f, tt, a.w);
                m20 = __builtin_amdgcn_fmed3f(m10, m20, h);
                m10 = fminf(m10, h);
                tt = p1.x * a.x; tt = fmaf(p1.y, a.y, tt); tt = fmaf(p1.z, a.z, tt);
                h = fmaf(-2.0f, tt, a.w);
                m21 = __builtin_amdgcn_fmed3f(m11, m21, h);
                m11 = fminf(m11, h);
            }
        }
        float d0 = fmaxf(p0.w + m20, 0.0f);
        float d1 = fmaxf(p1.w + m21, 0.0f);
        if (!(i0 == 0 && npad > 0)) sum += sqrtf(d0);
        if (a1) sum += sqrtf(d1);
    } else {
        for (int i = t; i < cntB; i += 256) {
            float4 pi = gpts[i];
            float m1 = 1e30f, m2 = 1e30f;
            for (int jt = 0; jt < cntB; jt += 8) {
                #pragma unroll
                for (int u = 0; u < 8; ++u) {
                    float4 a = gpts[jt + u];
                    float tt, h;
                    tt = pi.x * a.x; tt = fmaf(pi.y, a.y, tt); tt = fmaf(pi.z, a.z, tt);
                    h = fmaf(-2.0f, tt, a.w);
                    m2 = __builtin_amdgcn_fmed3f(m1, m2, h);
                    m1 = fminf(m1, h);
                }
            }
            float dmin = fmaxf(pi.w + m2, 0.0f);
            if (!(i == 0 && npad > 0)) sum += sqrtf(dmin);
        }
    }
    #pragma unroll
    for (int off = 32; off; off >>= 1) sum += __shfl_down(sum, off);
    if (lane == 0) s_part[wave] = sum;
    __syncthreads();
    if (t == 0) {
        float tot = s_part[0] + s_part[1] + s_part[2] + s_part[3] + 0.1f * (float)ns;
        float u  = tot / (float)ns;
        float du = u - P.expect_len;
        partials[xid] = du * du / (P.expect_len + 0.1f) * P.wscale[pidx];
    }
}

// ---------------------------------------------------------------------------
// Kernel 3: sum the 2040 per-block partials -> d_out (no atomics anywhere).
// ---------------------------------------------------------------------------
__global__ __launch_bounds__(256) void reduce_kernel(const float* __restrict__ partials,
                                                     float* __restrict__ out) {
    const int t = threadIdx.x;
    __shared__ float sp[4];
    float s = 0.0f;
    for (int i = t; i < NPART; i += 256) s += partials[i];
    #pragma unroll
    for (int off = 32; off; off >>= 1) s += __shfl_down(s, off);
    if ((t & 63) == 0) sp[t >> 6] = s;
    __syncthreads();
    if (t == 0) out[0] = sp[0] + sp[1] + sp[2] + sp[3];
}

extern "C" void kernel_launch(void* const* d_in, const int* in_sizes, int n_in,
                              void* d_out, int out_size, void* d_ws, size_t ws_size,
                              hipStream_t stream) {
    const float* pcd = (const float*)d_in[0];
    const int B = in_sizes[0] / (NPTS * 3);   // = 2
    float* out = (float*)d_out;
    int*   fps = (int*)d_ws;                  // [0, NGROUP) ints
    float* partials = (float*)d_ws + NGROUP;  // [NGROUP, NGROUP+NPART) floats

    fps_kernel<<<dim3(B), dim3(FPS_T), 0, stream>>>(pcd, fps);

    LossParams P;
    const double ps[NPCT] = {0.02, 0.04, 0.06, 0.08, 0.10};
    for (int i = 0; i < NPCT; ++i) {
        P.nsample[i] = (int)(NPTS * ps[i]);
        double r = std::sqrt(ps[i] * 1.0);
        P.r2[i] = (float)(r * r);
        double w = (ps[i] * 100.0) * (ps[i] * 100.0);
        P.wscale[i] = (float)(w / (double)(B * NPOINT * NPCT));
    }
    P.expect_len = (float)std::sqrt(3.14159265358979323846 / (double)NPTS);

    group_kernel<<<dim3(NPART), dim3(256), 0, stream>>>(pcd, fps, partials, P);
    reduce_kernel<<<dim3(1), dim3(256), 0, stream>>>(partials, out);
}